// Round 7
// baseline (237.964 us; speedup 1.0000x reference)
//
#include <hip/hip_runtime.h>
#include <hip/hip_bf16.h>

// Problem constants (fixed by the reference).
#define BB 32
#define SS 256
#define DD 256
#define UU 256
#define LL 16
#define DEG 16
#define NN (BB * SS)   // 8192 nodes
#define EE (NN * DEG)  // 131072 edges per branch
#define NSLICE 33      // slice 0 = self-loop, 1..16 = in labels, 17..32 = out labels
#define KMAIN (NSLICE * DD)   // 8448
#define KEXT 256              // ext cols: wsum/bias GEMM trick (34 slices total)
#define KTOT (KMAIN + KEXT)   // 8704 = 34*256
#define KSPLIT 17             // z owns slices {2z, 2z+1}; z=16 owns {32, ext}
#define TM 64
#define TN 256

using short8 = __attribute__((ext_vector_type(8))) short;  // 8 bf16 (4 VGPRs)
using f32x4  = __attribute__((ext_vector_type(4))) float;  // MFMA accumulator

// async global->LDS, 16B per lane, LDS dest = wave-uniform base + lane*16
#define GLDS(g, l)                                                        \
  __builtin_amdgcn_global_load_lds(                                       \
      (const __attribute__((address_space(1))) void*)(g),                 \
      (__attribute__((address_space(3))) void*)(l), 16, 0, 0)

__device__ __forceinline__ float bf2f(unsigned short v) {
  union { unsigned u; float f; } t;
  t.u = ((unsigned)v) << 16;
  return t.f;
}
__device__ __forceinline__ unsigned short f2bf(float f) {
  __hip_bfloat16 h = __float2bfloat16(f);
  return *(unsigned short*)&h;
}
__device__ __forceinline__ float sigm(float x) {
  return 1.f / (1.f + __expf(-x));
}

// ---------------------------------------------------------------------------
// K1 (merged): blocks [0,NN): prep (x cast + 3 gate dots).
// blocks [NN, NN+(NSLICE+1)*64): weight transpose + ext bias rows.
// ---------------------------------------------------------------------------
__global__ __launch_bounds__(256) void k_pre(
    const float* __restrict__ src, const float* __restrict__ gin,
    const float* __restrict__ gout, const float* __restrict__ gloop,
    const float* __restrict__ Vin, const float* __restrict__ Vout,
    const float* __restrict__ Wself, const float* __restrict__ b_in,
    const float* __restrict__ b_out,
    __hip_bfloat16* __restrict__ x_bf, float* __restrict__ xg_in,
    float* __restrict__ xg_out, float* __restrict__ xg_loop,
    __hip_bfloat16* __restrict__ Vt) {
  int bid = blockIdx.x;
  if (bid < NN) {
    int n = bid;
    int b = n / SS, s = n % SS;
    int d = threadIdx.x;
    float v = src[(size_t)(s * BB + b) * DD + d];
    x_bf[(size_t)n * DD + d] = __float2bfloat16(v);
    float p0 = v * gin[d], p1 = v * gout[d], p2 = v * gloop[d];
#pragma unroll
    for (int o = 32; o > 0; o >>= 1) {
      p0 += __shfl_down(p0, o);
      p1 += __shfl_down(p1, o);
      p2 += __shfl_down(p2, o);
    }
    __shared__ float r0[4], r1[4], r2[4];
    int w = threadIdx.x >> 6, lane = threadIdx.x & 63;
    if (lane == 0) { r0[w] = p0; r1[w] = p1; r2[w] = p2; }
    __syncthreads();
    if (threadIdx.x == 0) {
      xg_in[n]   = r0[0] + r0[1] + r0[2] + r0[3];
      xg_out[n]  = r1[0] + r1[1] + r1[2] + r1[3];
      xg_loop[n] = r2[0] + r2[1] + r2[2] + r2[3];
    }
    return;
  }
  int t = bid - NN;
  int z = t >> 6;                 // 0..NSLICE
  int rem = t & 63;
  int bx = rem & 7, by = rem >> 3;
  int tid = threadIdx.x;
  int tx = tid & 31, ty = tid >> 5;
  if (z == NSLICE) {              // ext bias rows: Vt[u][KMAIN+j] = bias_all[j][u]
    int u0 = bx * 32, j0 = by * 32;
#pragma unroll
    for (int i = 0; i < 4; i++) {
      int u = u0 + ty + i * 8, j = j0 + tx;
      float v = 0.f;
      if (j >= 1 && j <= LL)         v = b_in[(j - 1) * UU + u];
      else if (j > LL && j < NSLICE) v = b_out[(j - 1 - LL) * UU + u];
      Vt[(size_t)u * KTOT + KMAIN + j] = __float2bfloat16(v);
    }
    return;
  }
  __shared__ float tbuf[32][33];
  const float* srcM = (z == 0) ? Wself
                    : (z <= LL ? Vin  + (size_t)(z - 1)      * DD * UU
                               : Vout + (size_t)(z - 1 - LL) * DD * UU);
  int u0 = bx * 32, d0 = by * 32;
#pragma unroll
  for (int i = 0; i < 4; i++) {
    int dr = ty + i * 8;
    tbuf[dr][tx] = srcM[(size_t)(d0 + dr) * UU + u0 + tx];
  }
  __syncthreads();
#pragma unroll
  for (int i = 0; i < 4; i++) {
    int ur = ty + i * 8;
    Vt[(size_t)(u0 + ur) * KTOT + z * DD + d0 + tx] = __float2bfloat16(tbuf[tx][ur]);
  }
}

// ---------------------------------------------------------------------------
// K2: edge metadata, one wave per dst node. Builds per-node slice-sorted CSR:
//   ed[n*34 + 0]      = self edge {n, wl}
//   ed[n*34 + 1+rank] = label edge {src | (slice<<16), w}, sorted by slice
//   off[n*36 + s]     = start index of slice s in [0,34] (uint8)
//   wsumbuf[n*34 + j] = per-slice gate-weight sum (j=1..32; 0 at j=0,33)
// ---------------------------------------------------------------------------
__global__ __launch_bounds__(64) void k_meta(
    const float* __restrict__ xg_in, const float* __restrict__ xg_out,
    const float* __restrict__ xg_loop,
    const float* __restrict__ b_ing, const float* __restrict__ b_outg,
    const int* __restrict__ arc_in, const int* __restrict__ arc_out,
    const int* __restrict__ lab_in, const int* __restrict__ lab_out,
    const float* __restrict__ mask_in, const float* __restrict__ mask_out,
    const float* __restrict__ mask_loop,
    int2* __restrict__ ed, unsigned char* __restrict__ off,
    float* __restrict__ wsumbuf) {
  __shared__ int u_sl[32], u_src[32];
  __shared__ float u_w[32];
  int n = blockIdx.x, tid = threadIdx.x;
  if (tid < 32) {
    int br = tid >> 4, k = tid & 15;
    int e = n * DEG + k;
    const int* a = br ? arc_out : arc_in;
    int l = (br ? lab_out : lab_in)[e];
    int srcn = a[e] * SS + a[EE + e];
    float g = (br ? xg_out : xg_in)[srcn] + (br ? b_outg : b_ing)[l];
    u_sl[tid] = 1 + br * LL + l;
    u_src[tid] = srcn;
    u_w[tid] = sigm(g) * (br ? mask_out : mask_in)[e];
  }
  __syncthreads();
  if (tid < 32) {
    int my = u_sl[tid];
    int rank = 0;
#pragma unroll
    for (int j = 0; j < 32; j++) {
      int oj = u_sl[j];
      rank += (oj < my || (oj == my && j < tid)) ? 1 : 0;
    }
    ed[(size_t)n * 34 + 1 + rank] =
        make_int2(u_src[tid] | (my << 16), __float_as_int(u_w[tid]));
  }
  if (tid == 32) {
    float wl = sigm(xg_loop[n]) * mask_loop[n];
    ed[(size_t)n * 34] = make_int2(n, __float_as_int(wl));
  }
  if (tid < 35) {
    int cnt = 0;
#pragma unroll
    for (int j = 0; j < 32; j++) cnt += (u_sl[j] < tid) ? 1 : 0;
    off[(size_t)n * 36 + tid] = (unsigned char)((tid >= 1 ? 1 : 0) + cnt);
  }
  float ws = 0.f;
  if (tid >= 1 && tid < 33) {
#pragma unroll
    for (int j = 0; j < 32; j++) ws += (u_sl[j] == tid) ? u_w[j] : 0.f;
  }
  if (tid < 34) wsumbuf[(size_t)n * 34 + tid] = ws;
}

// ---------------------------------------------------------------------------
// K3: FUSED aggregation + bf16 MFMA GEMM. No Y intermediate: each K-iter's
// 64x32 A-tile is built in LDS from gathered x rows (x = 4 MB, L2-resident)
// via the per-node CSR. z owns slices {2z, 2z+1}; K-iter it -> slice
// s = 2z + (it>>3), d-chunk dc = it&7. Bs staged by GLDS, double-buffered,
// single-barrier pipelined. partial[z][n][u] bf16.
// ---------------------------------------------------------------------------
__global__ __launch_bounds__(256, 3) void k_gemm(
    const __hip_bfloat16* __restrict__ x, const __hip_bfloat16* __restrict__ Bt,
    const int2* __restrict__ ed, const unsigned char* __restrict__ off,
    const float* __restrict__ wsumbuf, __hip_bfloat16* __restrict__ partial) {
  __shared__ __align__(16) __hip_bfloat16 As[2][TM * 32];   // 8 KB
  __shared__ __align__(16) __hip_bfloat16 Bs[2][TN * 32];   // 32 KB
  int z = blockIdx.y;
  __hip_bfloat16* P = partial + (size_t)z * NN * UU;
  int row0 = blockIdx.x * TM;
  int tid = threadIdx.x;
  int w = tid >> 6, lane = tid & 63;
  int lrow = lane & 15, quad = lane >> 4;
  int sr = lane >> 2, sc = (lane & 3) * 8;  // Bs staging lane pattern
  int r = tid >> 2, q = tid & 3;            // A build: node row, col quarter
  int n = row0 + r;
  const unsigned short* xp = (const unsigned short*)x;

  auto STAGEB = [&](int bufi, int it) {
    int s = 2 * z + (it >> 3);
    int k0 = s * 256 + (it & 7) * 32;
#pragma unroll
    for (int t = 0; t < 4; t++) {
      int rb = (w * 4 + t) * 16;
      GLDS(&Bt[(size_t)(rb + sr) * KTOT + k0 + sc], &Bs[bufi][rb * 32]);
    }
  };

  auto BUILD = [&](int bufi, int it) {
    int s = 2 * z + (it >> 3);
    int dcol0 = (it & 7) * 32 + q * 8;
    float a[8] = {0.f, 0.f, 0.f, 0.f, 0.f, 0.f, 0.f, 0.f};
    if (s < 33) {
      int lo = off[(size_t)n * 36 + s];
      int hi = off[(size_t)n * 36 + s + 1];
      for (int e = lo; e < hi; e++) {
        int2 m = ed[(size_t)n * 34 + e];
        int srcn = m.x & 0xFFFF;
        float wv = __int_as_float(m.y);
        short8 v = *(const short8*)&xp[(size_t)srcn * DD + dcol0];
#pragma unroll
        for (int i = 0; i < 8; i++)
          a[i] += wv * bf2f((unsigned short)v[i]);
      }
    } else {  // ext slice: A[n][col] = wsum (col<34) else 0
#pragma unroll
      for (int i = 0; i < 8; i++) {
        int j = dcol0 + i;
        a[i] = (j < 34) ? wsumbuf[(size_t)n * 34 + j] : 0.f;
      }
    }
    short8 o;
#pragma unroll
    for (int i = 0; i < 8; i++) o[i] = (short)f2bf(a[i]);
    *(short8*)&As[bufi][r * 32 + q * 8] = o;
  };

  STAGEB(0, 0);
  BUILD(0, 0);
  f32x4 acc[4][4] = {};
  constexpr int NIT = 16;  // 2 slices x 8 d-chunks
  for (int it = 0; it < NIT; it++) {
    int cur = it & 1;
    __syncthreads();  // drains GLDS (vmcnt) + ds_writes (lgkmcnt) of prev stage
    if (it + 1 < NIT) {
      STAGEB(cur ^ 1, it + 1);
      BUILD(cur ^ 1, it + 1);
    }
    short8 af[4], bfr[4];
#pragma unroll
    for (int i = 0; i < 4; i++)
      af[i] = *(const short8*)&As[cur][(i * 16 + lrow) * 32 + quad * 8];
#pragma unroll
    for (int j = 0; j < 4; j++)
      bfr[j] = *(const short8*)&Bs[cur][(w * 64 + j * 16 + lrow) * 32 + quad * 8];
#pragma unroll
    for (int j = 0; j < 4; j++)
#pragma unroll
      for (int i = 0; i < 4; i++)
        acc[i][j] = __builtin_amdgcn_mfma_f32_16x16x32_bf16(af[i], bfr[j], acc[i][j], 0, 0, 0);
  }
  // C/D layout (m89/m91): col = lane&15, row = quad*4 + rr
#pragma unroll
  for (int i = 0; i < 4; i++)
#pragma unroll
    for (int j = 0; j < 4; j++) {
      int col = w * 64 + j * 16 + lrow;
      int rowb = row0 + i * 16 + quad * 4;
#pragma unroll
      for (int rr = 0; rr < 4; rr++)
        P[(size_t)(rowb + rr) * UU + col] = __float2bfloat16(acc[i][j][rr]);
    }
}

// ---------------------------------------------------------------------------
// K4: reduce KSPLIT bf16 partials + relu + sent_mask + transpose to out[s,b,u].
// ---------------------------------------------------------------------------
__global__ __launch_bounds__(64) void k_finish(
    const __hip_bfloat16* __restrict__ partial, const float* __restrict__ sent,
    float* __restrict__ out) {
  int n = blockIdx.x, u4 = threadIdx.x * 4;
  size_t idx = (size_t)n * UU + u4;
  const unsigned short* pp = (const unsigned short*)partial;
  float a0 = 0.f, a1 = 0.f, a2 = 0.f, a3 = 0.f;
#pragma unroll
  for (int z = 0; z < KSPLIT; z++) {
    ushort4 v = *(const ushort4*)&pp[(size_t)z * NN * UU + idx];
    a0 += bf2f(v.x); a1 += bf2f(v.y); a2 += bf2f(v.z); a3 += bf2f(v.w);
  }
  int s = n % SS, b = n / SS;
  float sm = sent[s * BB + b];
  float4 o;
  o.x = fmaxf(a0, 0.f) * sm; o.y = fmaxf(a1, 0.f) * sm;
  o.z = fmaxf(a2, 0.f) * sm; o.w = fmaxf(a3, 0.f) * sm;
  *(float4*)&out[((size_t)s * BB + b) * UU + u4] = o;
}

extern "C" void kernel_launch(void* const* d_in, const int* in_sizes, int n_in,
                              void* d_out, int out_size, void* d_ws, size_t ws_size,
                              hipStream_t stream) {
  const float* src      = (const float*)d_in[0];
  const float* V_in     = (const float*)d_in[1];
  const float* b_in     = (const float*)d_in[2];
  const float* V_ing    = (const float*)d_in[3];
  const float* b_ing    = (const float*)d_in[4];
  const float* V_out    = (const float*)d_in[5];
  const float* b_out    = (const float*)d_in[6];
  const float* V_outg   = (const float*)d_in[7];
  const float* b_outg   = (const float*)d_in[8];
  const float* W_self   = (const float*)d_in[9];
  const float* W_selfg  = (const float*)d_in[10];
  const int* arc_in     = (const int*)d_in[11];
  const int* arc_out    = (const int*)d_in[12];
  const int* lab_in     = (const int*)d_in[13];
  const int* lab_out    = (const int*)d_in[14];
  const float* mask_in  = (const float*)d_in[15];
  const float* mask_out = (const float*)d_in[16];
  const float* mask_loop= (const float*)d_in[17];
  const float* sent     = (const float*)d_in[18];
  float* out = (float*)d_out;

  char* ws = (char*)d_ws;
  size_t off_b = 0;
  auto alloc = [&](size_t bytes) -> void* {
    void* p = ws + off_b;
    off_b += (bytes + 255) & ~(size_t)255;
    return p;
  };
  __hip_bfloat16* x_bf = (__hip_bfloat16*)alloc((size_t)NN * DD * 2);       // 4 MB
  __hip_bfloat16* Vt   = (__hip_bfloat16*)alloc((size_t)UU * KTOT * 2);     // 4.5 MB
  float* xg_in   = (float*)alloc(NN * 4);
  float* xg_out  = (float*)alloc(NN * 4);
  float* xg_loop = (float*)alloc(NN * 4);
  int2* ed       = (int2*)alloc((size_t)NN * 34 * 8);                       // 2.2 MB
  unsigned char* offb = (unsigned char*)alloc((size_t)NN * 36);             // 0.3 MB
  float* wsumbuf = (float*)alloc((size_t)NN * 34 * 4);                      // 1.1 MB
  __hip_bfloat16* partial =
      (__hip_bfloat16*)alloc((size_t)KSPLIT * NN * UU * 2);                 // 71 MB

  k_pre<<<NN + (NSLICE + 1) * 64, 256, 0, stream>>>(
      src, V_ing, V_outg, W_selfg, V_in, V_out, W_self, b_in, b_out,
      x_bf, xg_in, xg_out, xg_loop, Vt);
  k_meta<<<NN, 64, 0, stream>>>(xg_in, xg_out, xg_loop, b_ing, b_outg,
                                arc_in, arc_out, lab_in, lab_out,
                                mask_in, mask_out, mask_loop,
                                ed, offb, wsumbuf);
  k_gemm<<<dim3(NN / TM, KSPLIT), 256, 0, stream>>>(x_bf, Vt, ed, offb,
                                                    wsumbuf, partial);
  k_finish<<<NN, 64, 0, stream>>>(partial, sent, out);
}

// Round 8
// 193.321 us; speedup vs baseline: 1.2309x; 1.2309x over previous
//
#include <hip/hip_runtime.h>
#include <hip/hip_bf16.h>

// Problem constants (fixed by the reference).
#define BB 32
#define SS 256
#define DD 256
#define UU 256
#define LL 16
#define DEG 16
#define NN (BB * SS)   // 8192 nodes
#define EE (NN * DEG)  // 131072 edges per branch
#define NSLICE 33      // slice 0 = self-loop, 1..16 = in labels, 17..32 = out labels
#define KMAIN (NSLICE * DD)   // 8448
#define KEXT 256              // ext cols: wsum/bias GEMM trick (33 used, rest 0)
#define KTOT (KMAIN + KEXT)   // 8704 = 34*256
#define KSPLIT 8
#define KS (KTOT / KSPLIT)    // 1088 = 34*32
#define TM 128
#define TN 256

using short8 = __attribute__((ext_vector_type(8))) short;  // 8 bf16 (4 VGPRs)
using f32x4  = __attribute__((ext_vector_type(4))) float;  // MFMA accumulator

// async global->LDS, 16B per lane, LDS dest = wave-uniform base + lane*16
#define GLDS(g, l)                                                        \
  __builtin_amdgcn_global_load_lds(                                       \
      (const __attribute__((address_space(1))) void*)(g),                 \
      (__attribute__((address_space(3))) void*)(l), 16, 0, 0)

__device__ __forceinline__ float bf2f(unsigned short v) {
  union { unsigned u; float f; } t;
  t.u = ((unsigned)v) << 16;
  return t.f;
}
__device__ __forceinline__ unsigned short f2bf(float f) {
  __hip_bfloat16 h = __float2bfloat16(f);
  return *(unsigned short*)&h;
}
__device__ __forceinline__ float sigm(float x) {
  return 1.f / (1.f + __expf(-x));
}

// ---------------------------------------------------------------------------
// K1 (merged): blocks [0,NN): prep (x cast + 3 gate dots).
// blocks [NN, NN+(NSLICE+1)*64): weight transpose + ext bias rows.
// ---------------------------------------------------------------------------
__global__ __launch_bounds__(256) void k_pre(
    const float* __restrict__ src, const float* __restrict__ gin,
    const float* __restrict__ gout, const float* __restrict__ gloop,
    const float* __restrict__ Vin, const float* __restrict__ Vout,
    const float* __restrict__ Wself, const float* __restrict__ b_in,
    const float* __restrict__ b_out,
    __hip_bfloat16* __restrict__ x_bf, float* __restrict__ xg_in,
    float* __restrict__ xg_out, float* __restrict__ xg_loop,
    __hip_bfloat16* __restrict__ Vt) {
  int bid = blockIdx.x;
  if (bid < NN) {
    int n = bid;
    int b = n / SS, s = n % SS;
    int d = threadIdx.x;
    float v = src[(size_t)(s * BB + b) * DD + d];
    x_bf[(size_t)n * DD + d] = __float2bfloat16(v);
    float p0 = v * gin[d], p1 = v * gout[d], p2 = v * gloop[d];
#pragma unroll
    for (int o = 32; o > 0; o >>= 1) {
      p0 += __shfl_down(p0, o);
      p1 += __shfl_down(p1, o);
      p2 += __shfl_down(p2, o);
    }
    __shared__ float r0[4], r1[4], r2[4];
    int w = threadIdx.x >> 6, lane = threadIdx.x & 63;
    if (lane == 0) { r0[w] = p0; r1[w] = p1; r2[w] = p2; }
    __syncthreads();
    if (threadIdx.x == 0) {
      xg_in[n]   = r0[0] + r0[1] + r0[2] + r0[3];
      xg_out[n]  = r1[0] + r1[1] + r1[2] + r1[3];
      xg_loop[n] = r2[0] + r2[1] + r2[2] + r2[3];
    }
    return;
  }
  int t = bid - NN;
  int z = t >> 6;                 // 0..NSLICE
  int rem = t & 63;
  int bx = rem & 7, by = rem >> 3;
  int tid = threadIdx.x;
  int tx = tid & 31, ty = tid >> 5;
  if (z == NSLICE) {              // ext bias rows: Vt[u][KMAIN+j] = bias_all[j][u]
    int u0 = bx * 32, j0 = by * 32;
#pragma unroll
    for (int i = 0; i < 4; i++) {
      int u = u0 + ty + i * 8, j = j0 + tx;
      float v = 0.f;
      if (j >= 1 && j <= LL)         v = b_in[(j - 1) * UU + u];
      else if (j > LL && j < NSLICE) v = b_out[(j - 1 - LL) * UU + u];
      Vt[(size_t)u * KTOT + KMAIN + j] = __float2bfloat16(v);
    }
    return;
  }
  __shared__ float tbuf[32][33];
  const float* srcM = (z == 0) ? Wself
                    : (z <= LL ? Vin  + (size_t)(z - 1)      * DD * UU
                               : Vout + (size_t)(z - 1 - LL) * DD * UU);
  int u0 = bx * 32, d0 = by * 32;
#pragma unroll
  for (int i = 0; i < 4; i++) {
    int dr = ty + i * 8;
    tbuf[dr][tx] = srcM[(size_t)(d0 + dr) * UU + u0 + tx];
  }
  __syncthreads();
#pragma unroll
  for (int i = 0; i < 4; i++) {
    int ur = ty + i * 8;
    Vt[(size_t)(u0 + ur) * KTOT + z * DD + d0 + tx] = __float2bfloat16(tbuf[tx][ur]);
  }
}

// ---------------------------------------------------------------------------
// K3: aggregation, one WAVE per dst node (round-6 version, proven).
// Y[n][slice*256+d]; ext col j = per-slice gate-weight sum.
// ---------------------------------------------------------------------------
__global__ __launch_bounds__(64) void k_agg(
    const __hip_bfloat16* __restrict__ x,
    const float* __restrict__ xg_in, const float* __restrict__ xg_out,
    const float* __restrict__ xg_loop,
    const float* __restrict__ b_ing, const float* __restrict__ b_outg,
    const int* __restrict__ arc_in, const int* __restrict__ arc_out,
    const int* __restrict__ lab_in, const int* __restrict__ lab_out,
    const float* __restrict__ mask_in, const float* __restrict__ mask_out,
    const float* __restrict__ mask_loop,
    __hip_bfloat16* __restrict__ Y) {
  __shared__ int u_sl[32], u_src[32];
  __shared__ float u_w[32];
  __shared__ int s_sl[32], s_src[32];
  __shared__ float s_w[32];
  __shared__ float s_wsum[NSLICE];
  int n = blockIdx.x, tid = threadIdx.x;
  if (tid < 32) {
    int br = tid >> 4, k = tid & 15;
    int e = n * DEG + k;
    const int* a = br ? arc_out : arc_in;
    int l = (br ? lab_out : lab_in)[e];
    int srcn = a[e] * SS + a[EE + e];
    float g = (br ? xg_out : xg_in)[srcn] + (br ? b_outg : b_ing)[l];
    u_sl[tid] = 1 + br * LL + l;
    u_src[tid] = srcn;
    u_w[tid] = sigm(g) * (br ? mask_out : mask_in)[e];
  }
  __syncthreads();
  if (tid < 32) {
    int my = u_sl[tid];
    int rank = 0;
#pragma unroll
    for (int j = 0; j < 32; j++) {
      int oj = u_sl[j];
      rank += (oj < my || (oj == my && j < tid)) ? 1 : 0;
    }
    s_sl[rank] = my;
    s_src[rank] = u_src[tid];
    s_w[rank] = u_w[tid];
  }
  __syncthreads();

  const unsigned short* xp = (const unsigned short*)x;
  unsigned short* yp = (unsigned short*)Y;
  size_t base = (size_t)n * KTOT;
  int d4 = tid * 4;
  {
    float wl = sigm(xg_loop[n]) * mask_loop[n];
    ushort4 v = *(const ushort4*)&xp[(size_t)n * DD + d4];
    ushort4 o;
    o.x = f2bf(wl * bf2f(v.x)); o.y = f2bf(wl * bf2f(v.y));
    o.z = f2bf(wl * bf2f(v.z)); o.w = f2bf(wl * bf2f(v.w));
    *(ushort4*)&yp[base + d4] = o;
  }
  unsigned long long present = 0ull;
  float a0 = 0.f, a1 = 0.f, a2 = 0.f, a3 = 0.f, ws = 0.f;
#pragma unroll
  for (int e = 0; e < 32; e++) {
    int sl = s_sl[e];
    int srcn = s_src[e];
    float w = s_w[e];
    ushort4 v = *(const ushort4*)&xp[(size_t)srcn * DD + d4];
    a0 += w * bf2f(v.x); a1 += w * bf2f(v.y);
    a2 += w * bf2f(v.z); a3 += w * bf2f(v.w);
    ws += w;
    int slnext = (e < 31) ? s_sl[e + 1] : 999;
    if (sl != slnext) {
      ushort4 o;
      o.x = f2bf(a0); o.y = f2bf(a1); o.z = f2bf(a2); o.w = f2bf(a3);
      *(ushort4*)&yp[base + sl * DD + d4] = o;
      if (tid == 0) s_wsum[sl] = ws;
      present |= (1ull << sl);
      a0 = a1 = a2 = a3 = ws = 0.f;
    }
  }
  ushort4 zero4 = {0, 0, 0, 0};
#pragma unroll
  for (int s = 1; s < NSLICE; s++) {
    if (!((present >> s) & 1ull)) {
      *(ushort4*)&yp[base + s * DD + d4] = zero4;
      if (tid == 0) s_wsum[s] = 0.f;
    }
  }
  __syncthreads();
  {
    ushort4 o;
    unsigned short* op = (unsigned short*)&o;
#pragma unroll
    for (int c = 0; c < 4; c++) {
      int j = d4 + c;
      float v = (j >= 1 && j < NSLICE) ? s_wsum[j] : 0.f;
      op[c] = f2bf(v);
    }
    *(ushort4*)&yp[base + KMAIN + d4] = o;
  }
}

// ---------------------------------------------------------------------------
// K4: bf16 MFMA GEMM with AITER-style fine-grained waits. 3-stage LDS
// pipeline, prefetch distance 2. Per iter: s_waitcnt vmcnt(6) (drains only
// the stage about to be consumed: 6 GLDS/wave issued 2 iters ago) + raw
// s_barrier — prefetches stay in flight across the barrier. Tile 128x256
// (full U -> A read once), 4 waves, wave w owns cols [w*64,w*64+64):
// 8x4 frags of 16x16x32. grid (NN/TM, KSPLIT); partial[z][n][u] bf16.
// Safety: each wave drains its own stage-k GLDS before the barrier, so after
// the barrier all waves' stage-k LDS data is visible; ds_reads of iter i are
// consumed by MFMA (lgkm-waited) before barrier i+1, so overwriting buffer
// (i+2)%3 == (i-1)%3 after that barrier cannot race.
// ---------------------------------------------------------------------------
__global__ __launch_bounds__(256, 2) void k_gemm(
    const __hip_bfloat16* __restrict__ A, const __hip_bfloat16* __restrict__ Bt,
    __hip_bfloat16* __restrict__ partial) {
  __shared__ __align__(16) __hip_bfloat16 As[3][TM * 32];   // 24 KB
  __shared__ __align__(16) __hip_bfloat16 Bs[3][TN * 32];   // 48 KB
  __hip_bfloat16* P = partial + (size_t)blockIdx.y * NN * UU;
  int kbeg = blockIdx.y * KS;
  int row0 = blockIdx.x * TM;
  int tid = threadIdx.x;
  int w = tid >> 6, lane = tid & 63;
  int lrow = lane & 15, quad = lane >> 4;
  int sr = lane >> 2;          // staging: row within 16-row group
  int sc = (lane & 3) * 8;     // staging: k-offset (elements)

#define STAGE(bufi, it)                                                     \
  {                                                                         \
    int k0 = kbeg + (it) * 32;                                              \
    _Pragma("unroll")                                                       \
    for (int t = 0; t < 2; t++) {                                           \
      int rb = (w * 2 + t) * 16;                                            \
      GLDS(&A[(size_t)(row0 + rb + sr) * KTOT + k0 + sc],                   \
           &As[bufi][rb * 32]);                                             \
    }                                                                       \
    _Pragma("unroll")                                                       \
    for (int t = 0; t < 4; t++) {                                           \
      int rb = (w * 4 + t) * 16;                                            \
      GLDS(&Bt[(size_t)(rb + sr) * KTOT + k0 + sc], &Bs[bufi][rb * 32]);    \
    }                                                                       \
  }

  constexpr int NIT = KS / 32;   // 34
  STAGE(0, 0);
  STAGE(1, 1);
  f32x4 acc[8][4] = {};

#define COMPUTE(cur)                                                        \
  {                                                                         \
    short8 af[8], bfr[4];                                                   \
    _Pragma("unroll")                                                       \
    for (int i = 0; i < 8; i++)                                             \
      af[i] = *(const short8*)&As[cur][(i * 16 + lrow) * 32 + quad * 8];    \
    _Pragma("unroll")                                                       \
    for (int j = 0; j < 4; j++)                                             \
      bfr[j] = *(const short8*)&Bs[cur][(w * 64 + j * 16 + lrow) * 32 + quad * 8]; \
    _Pragma("unroll")                                                       \
    for (int j = 0; j < 4; j++)                                             \
      _Pragma("unroll")                                                     \
      for (int i = 0; i < 8; i++)                                           \
        acc[i][j] = __builtin_amdgcn_mfma_f32_16x16x32_bf16(af[i], bfr[j],  \
                                                            acc[i][j], 0, 0, 0); \
  }

  for (int it = 0; it < NIT - 1; it++) {
    // wait until only the 6 newest GLDS remain -> oldest stage (it) is done
    asm volatile("s_waitcnt vmcnt(6)" ::: "memory");
    __builtin_amdgcn_s_barrier();
    if (it + 2 < NIT) STAGE((it + 2) % 3, it + 2);
    COMPUTE(it % 3);
  }
  asm volatile("s_waitcnt vmcnt(0)" ::: "memory");
  __builtin_amdgcn_s_barrier();
  COMPUTE((NIT - 1) % 3);
#undef STAGE
#undef COMPUTE

  // C/D layout (m89/m91): col = lane&15, row = quad*4 + r
#pragma unroll
  for (int i = 0; i < 8; i++)
#pragma unroll
    for (int j = 0; j < 4; j++) {
      int col = w * 64 + j * 16 + lrow;
      int rowb = row0 + i * 16 + quad * 4;
#pragma unroll
      for (int r = 0; r < 4; r++)
        P[(size_t)(rowb + r) * UU + col] = __float2bfloat16(acc[i][j][r]);
    }
}

// ---------------------------------------------------------------------------
// K5: reduce KSPLIT bf16 partials + relu + sent_mask + transpose to out[s,b,u].
// ---------------------------------------------------------------------------
__global__ __launch_bounds__(64) void k_finish(
    const __hip_bfloat16* __restrict__ partial, const float* __restrict__ sent,
    float* __restrict__ out) {
  int n = blockIdx.x, u4 = threadIdx.x * 4;
  size_t idx = (size_t)n * UU + u4;
  const unsigned short* pp = (const unsigned short*)partial;
  float a0 = 0.f, a1 = 0.f, a2 = 0.f, a3 = 0.f;
#pragma unroll
  for (int z = 0; z < KSPLIT; z++) {
    ushort4 v = *(const ushort4*)&pp[(size_t)z * NN * UU + idx];
    a0 += bf2f(v.x); a1 += bf2f(v.y); a2 += bf2f(v.z); a3 += bf2f(v.w);
  }
  int s = n % SS, b = n / SS;
  float sm = sent[s * BB + b];
  float4 o;
  o.x = fmaxf(a0, 0.f) * sm; o.y = fmaxf(a1, 0.f) * sm;
  o.z = fmaxf(a2, 0.f) * sm; o.w = fmaxf(a3, 0.f) * sm;
  *(float4*)&out[((size_t)s * BB + b) * UU + u4] = o;
}

extern "C" void kernel_launch(void* const* d_in, const int* in_sizes, int n_in,
                              void* d_out, int out_size, void* d_ws, size_t ws_size,
                              hipStream_t stream) {
  const float* src      = (const float*)d_in[0];
  const float* V_in     = (const float*)d_in[1];
  const float* b_in     = (const float*)d_in[2];
  const float* V_ing    = (const float*)d_in[3];
  const float* b_ing    = (const float*)d_in[4];
  const float* V_out    = (const float*)d_in[5];
  const float* b_out    = (const float*)d_in[6];
  const float* V_outg   = (const float*)d_in[7];
  const float* b_outg   = (const float*)d_in[8];
  const float* W_self   = (const float*)d_in[9];
  const float* W_selfg  = (const float*)d_in[10];
  const int* arc_in     = (const int*)d_in[11];
  const int* arc_out    = (const int*)d_in[12];
  const int* lab_in     = (const int*)d_in[13];
  const int* lab_out    = (const int*)d_in[14];
  const float* mask_in  = (const float*)d_in[15];
  const float* mask_out = (const float*)d_in[16];
  const float* mask_loop= (const float*)d_in[17];
  const float* sent     = (const float*)d_in[18];
  float* out = (float*)d_out;

  char* ws = (char*)d_ws;
  size_t off = 0;
  auto alloc = [&](size_t bytes) -> void* {
    void* p = ws + off;
    off += (bytes + 255) & ~(size_t)255;
    return p;
  };
  __hip_bfloat16* x_bf = (__hip_bfloat16*)alloc((size_t)NN * DD * 2);       // 4 MB
  __hip_bfloat16* Vt   = (__hip_bfloat16*)alloc((size_t)UU * KTOT * 2);     // 4.5 MB
  float* xg_in   = (float*)alloc(NN * 4);
  float* xg_out  = (float*)alloc(NN * 4);
  float* xg_loop = (float*)alloc(NN * 4);
  __hip_bfloat16* Y = (__hip_bfloat16*)alloc((size_t)NN * KTOT * 2);        // 143 MB
  __hip_bfloat16* partial =
      (__hip_bfloat16*)alloc((size_t)KSPLIT * NN * UU * 2);                 // 34 MB

  k_pre<<<NN + (NSLICE + 1) * 64, 256, 0, stream>>>(
      src, V_ing, V_outg, W_selfg, V_in, V_out, W_self, b_in, b_out,
      x_bf, xg_in, xg_out, xg_loop, Vt);
  k_agg<<<NN, 64, 0, stream>>>(x_bf, xg_in, xg_out, xg_loop, b_ing, b_outg,
                               arc_in, arc_out, lab_in, lab_out,
                               mask_in, mask_out, mask_loop, Y);
  k_gemm<<<dim3(NN / TM, KSPLIT), 256, 0, stream>>>(Y, Vt, partial);
  k_finish<<<NN, 64, 0, stream>>>(partial, sent, out);
}